// Round 8
// baseline (157.771 us; speedup 1.0000x reference)
//
#include <hip/hip_runtime.h>
#include <hip/hip_bf16.h>

// ListMLE: mean(cumlogsumexp(gather(outputs, labels), axis=1) - outputs)
// B=8192 rows, N=4096 cols. outputs fp32, labels int32 (per-row permutation).
// R8: R6's pipeline x R7's small-LDS, composed.
//  - ROWS=4 rows/block, grid 2048 = exactly 8 blocks/CU (32 waves, wave-capped)
//  - LDS double buffer of bf16 e-values: 2 x 8 KB (R6 was 2 x 16 KB fp32 -> 4 blocks/CU)
//  - next row's outputs+labels prefetched into regs during current row compute
//  - xsum computed in fp32 from regs at STAGING time (one row early, carried),
//    since the gather path only ever sees bf16 e-values
//  - staging (vmcnt wait + convert + ds_write) placed before the 16 log2s
//  - mid-row barrier is lgkm-only so prefetch loads stay in flight
//  - launch_bounds(256,8): VGPR cap 64; R6's same live set needed 52

#define N_COLS 4096
#define BLOCK 256
#define PER_THREAD (N_COLS / BLOCK)  // 16
#define NWAVES (BLOCK / 64)          // 4
#define ROWS 4
#define LOG2E 1.4426950408889634f
#define LN2   0.6931471805599453f

__device__ __forceinline__ unsigned short f2bf(float f) {
    union { float f; unsigned u; } v; v.f = f;
    unsigned u = v.u + 0x7FFF + ((v.u >> 16) & 1);   // round-to-nearest-even
    return (unsigned short)(u >> 16);
}
__device__ __forceinline__ float bf2f(unsigned short h) {
    union { unsigned u; float f; } v; v.u = ((unsigned)h) << 16;
    return v.f;
}

__global__ __launch_bounds__(BLOCK, 8) void listmle_rows_kernel(
    const float* __restrict__ outputs,
    const int*   __restrict__ labels,
    double*      __restrict__ partials)
{
    __shared__ unsigned short ebuf[2][N_COLS];   // 2 x 8 KB bf16 e-values
    __shared__ float wave_t[NWAVES];
    __shared__ float wsum[NWAVES];

    const int tid  = threadIdx.x;
    const int lane = tid & 63;
    const int wid  = tid >> 6;
    const size_t row0  = (size_t)blockIdx.x * ROWS;
    const int    start = tid * PER_THREAD;

    // ---- prologue: row 0 -> regs; xsum0; stage buf 0 ----
    int4   lf0, lf1, lf2, lf3;
    float4 of0, of1, of2, of3;
    {
        const int4* lrow = (const int4*)(labels + row0 * N_COLS + start);
        lf0 = lrow[0]; lf1 = lrow[1]; lf2 = lrow[2]; lf3 = lrow[3];
        const float4* orow = (const float4*)(outputs + row0 * N_COLS);
        of0 = orow[tid];       of1 = orow[tid + 256];
        of2 = orow[tid + 512]; of3 = orow[tid + 768];
    }
    float xsum_cur = (of0.x + of0.y + of0.z + of0.w)
                   + (of1.x + of1.y + of1.z + of1.w)
                   + (of2.x + of2.y + of2.z + of2.w)
                   + (of3.x + of3.y + of3.z + of3.w);
    {
        ushort4* e4 = (ushort4*)ebuf[0];
        ushort4 s;
        s.x = f2bf(exp2f(of0.x * LOG2E)); s.y = f2bf(exp2f(of0.y * LOG2E));
        s.z = f2bf(exp2f(of0.z * LOG2E)); s.w = f2bf(exp2f(of0.w * LOG2E));
        e4[tid] = s;
        s.x = f2bf(exp2f(of1.x * LOG2E)); s.y = f2bf(exp2f(of1.y * LOG2E));
        s.z = f2bf(exp2f(of1.z * LOG2E)); s.w = f2bf(exp2f(of1.w * LOG2E));
        e4[tid + 256] = s;
        s.x = f2bf(exp2f(of2.x * LOG2E)); s.y = f2bf(exp2f(of2.y * LOG2E));
        s.z = f2bf(exp2f(of2.z * LOG2E)); s.w = f2bf(exp2f(of2.w * LOG2E));
        e4[tid + 512] = s;
        s.x = f2bf(exp2f(of3.x * LOG2E)); s.y = f2bf(exp2f(of3.y * LOG2E));
        s.z = f2bf(exp2f(of3.z * LOG2E)); s.w = f2bf(exp2f(of3.w * LOG2E));
        e4[tid + 768] = s;
    }
    __syncthreads();

    float total_contrib = 0.0f;
    int cur = 0;

    for (int k = 0; k < ROWS; ++k) {
        // current row labels -> static-indexed array
        int labs[PER_THREAD] = { lf0.x, lf0.y, lf0.z, lf0.w,
                                 lf1.x, lf1.y, lf1.z, lf1.w,
                                 lf2.x, lf2.y, lf2.z, lf2.w,
                                 lf3.x, lf3.y, lf3.z, lf3.w };

        // issue next-row loads (labels first, outputs second)
        if (k + 1 < ROWS) {
            const int4* lrow = (const int4*)(labels + (row0 + k + 1) * N_COLS + start);
            lf0 = lrow[0]; lf1 = lrow[1]; lf2 = lrow[2]; lf3 = lrow[3];
            const float4* orow = (const float4*)(outputs + (row0 + k + 1) * N_COLS);
            of0 = orow[tid];       of1 = orow[tid + 256];
            of2 = orow[tid + 512]; of3 = orow[tid + 768];
        }

        // gather bf16 e-values in label order; thread-local prefix sums
        const unsigned short* cb = ebuf[cur];
        float p[PER_THREAD];
        float run = 0.0f;
        #pragma unroll
        for (int j = 0; j < PER_THREAD; ++j) {
            run += bf2f(cb[labs[j]]);
            p[j] = run;
        }

        // wave-level inclusive scan of thread totals
        float inc = run;
        #pragma unroll
        for (int d = 1; d < 64; d <<= 1) {
            float v = __shfl_up(inc, d, 64);
            if (lane >= d) inc += v;
        }
        float excl = inc - run;
        if (lane == 63) wave_t[wid] = inc;

        // lgkm-only barrier: prefetch loads stay in flight
        asm volatile("s_waitcnt lgkmcnt(0)" ::: "memory");
        __builtin_amdgcn_s_barrier();

        float E = excl;
        #pragma unroll
        for (int w = 0; w < NWAVES - 1; ++w)
            if (w < wid) E += wave_t[w];

        // stage next row (vmcnt wait lands here); overlapped with log2s below
        float xsum_next = 0.0f;
        if (k + 1 < ROWS) {
            xsum_next = (of0.x + of0.y + of0.z + of0.w)
                      + (of1.x + of1.y + of1.z + of1.w)
                      + (of2.x + of2.y + of2.z + of2.w)
                      + (of3.x + of3.y + of3.z + of3.w);
            ushort4* e4 = (ushort4*)ebuf[cur ^ 1];
            ushort4 s;
            s.x = f2bf(exp2f(of0.x * LOG2E)); s.y = f2bf(exp2f(of0.y * LOG2E));
            s.z = f2bf(exp2f(of0.z * LOG2E)); s.w = f2bf(exp2f(of0.w * LOG2E));
            e4[tid] = s;
            s.x = f2bf(exp2f(of1.x * LOG2E)); s.y = f2bf(exp2f(of1.y * LOG2E));
            s.z = f2bf(exp2f(of1.z * LOG2E)); s.w = f2bf(exp2f(of1.w * LOG2E));
            e4[tid + 256] = s;
            s.x = f2bf(exp2f(of2.x * LOG2E)); s.y = f2bf(exp2f(of2.y * LOG2E));
            s.z = f2bf(exp2f(of2.z * LOG2E)); s.w = f2bf(exp2f(of2.w * LOG2E));
            e4[tid + 512] = s;
            s.x = f2bf(exp2f(of3.x * LOG2E)); s.y = f2bf(exp2f(of3.y * LOG2E));
            s.z = f2bf(exp2f(of3.z * LOG2E)); s.w = f2bf(exp2f(of3.w * LOG2E));
            e4[tid + 768] = s;
        }

        // scores: 16 independent log2s (overlap the staging writes)
        float acc = 0.0f;
        #pragma unroll
        for (int j = 0; j < PER_THREAD; ++j)
            acc += __log2f(E + p[j]);
        total_contrib += LN2 * acc - xsum_cur;
        xsum_cur = xsum_next;

        __syncthreads();   // row boundary: buffer cur^1 fully staged
        cur ^= 1;
    }

    // ---- block reduce total contribution, plain store per block ----
    #pragma unroll
    for (int d = 32; d > 0; d >>= 1)
        total_contrib += __shfl_down(total_contrib, d, 64);
    if (lane == 0) wsum[wid] = total_contrib;
    __syncthreads();
    if (tid == 0) {
        float tot = 0.0f;
        #pragma unroll
        for (int w = 0; w < NWAVES; ++w) tot += wsum[w];
        partials[blockIdx.x] = (double)tot;
    }
}

// One block: reduce partial doubles, write mean as float.
__global__ __launch_bounds__(BLOCK) void listmle_reduce_kernel(
    const double* __restrict__ partials,
    float* __restrict__ out,
    int nblocks,
    double inv_count)
{
    __shared__ double wtot[NWAVES];
    const int tid  = threadIdx.x;
    const int lane = tid & 63;
    const int wid  = tid >> 6;

    double sum = 0.0;
    for (int i = tid; i < nblocks; i += BLOCK)
        sum += partials[i];

    #pragma unroll
    for (int d = 32; d > 0; d >>= 1)
        sum += __shfl_down(sum, d, 64);
    if (lane == 0) wtot[wid] = sum;
    __syncthreads();
    if (tid == 0) {
        double tot = 0.0;
        #pragma unroll
        for (int w = 0; w < NWAVES; ++w) tot += wtot[w];
        out[0] = (float)(tot * inv_count);
    }
}

extern "C" void kernel_launch(void* const* d_in, const int* in_sizes, int n_in,
                              void* d_out, int out_size, void* d_ws, size_t ws_size,
                              hipStream_t stream)
{
    const float* outputs = (const float*)d_in[0];
    const int*   labels  = (const int*)d_in[1];
    float*  out = (float*)d_out;
    double* partials = (double*)d_ws;

    const int total = in_sizes[0];          // B * N
    const int B = total / N_COLS;           // 8192
    const int nblocks = B / ROWS;           // 2048

    listmle_rows_kernel<<<nblocks, BLOCK, 0, stream>>>(outputs, labels, partials);
    listmle_reduce_kernel<<<1, BLOCK, 0, stream>>>(partials, out, nblocks,
                                                   1.0 / (double)total);
}

// Round 9
// 142.442 us; speedup vs baseline: 1.1076x; 1.1076x over previous
//
#include <hip/hip_runtime.h>
#include <hip/hip_bf16.h>

// ListMLE: mean(cumlogsumexp(gather(outputs, labels), axis=1) - outputs)
// B=8192 rows, N=4096 cols. outputs fp32, labels int32 (per-row permutation).
// R9: R8 composition (pipeline + bf16 e-value double buffer) with the register
//     cap relaxed one notch: launch_bounds(256,6) -> VGPR cap ~84.
//     R8's (256,8)=64-cap spilled (WRITE_SIZE 303MB): live set = 32 prefetch
//     VGPRs + p[16] + scan temps ~= 70-80. R6's near-identical set was 52 @128.
//     6 blocks/CU x 4 waves = 24 waves/CU (R6 had 16), LDS 16.9KB not binding.

#define N_COLS 4096
#define BLOCK 256
#define PER_THREAD (N_COLS / BLOCK)  // 16
#define NWAVES (BLOCK / 64)          // 4
#define ROWS 4
#define LOG2E 1.4426950408889634f
#define LN2   0.6931471805599453f

__device__ __forceinline__ unsigned short f2bf(float f) {
    union { float f; unsigned u; } v; v.f = f;
    unsigned u = v.u + 0x7FFF + ((v.u >> 16) & 1);   // round-to-nearest-even
    return (unsigned short)(u >> 16);
}
__device__ __forceinline__ float bf2f(unsigned short h) {
    union { unsigned u; float f; } v; v.u = ((unsigned)h) << 16;
    return v.f;
}

__global__ __launch_bounds__(BLOCK, 6) void listmle_rows_kernel(
    const float* __restrict__ outputs,
    const int*   __restrict__ labels,
    double*      __restrict__ partials)
{
    __shared__ unsigned short ebuf[2][N_COLS];   // 2 x 8 KB bf16 e-values
    __shared__ float wave_t[NWAVES];
    __shared__ float wsum[NWAVES];

    const int tid  = threadIdx.x;
    const int lane = tid & 63;
    const int wid  = tid >> 6;
    const size_t row0  = (size_t)blockIdx.x * ROWS;
    const int    start = tid * PER_THREAD;

    // ---- prologue: row 0 -> regs; xsum0; stage buf 0 ----
    int4   lf0, lf1, lf2, lf3;
    float4 of0, of1, of2, of3;
    {
        const int4* lrow = (const int4*)(labels + row0 * N_COLS + start);
        lf0 = lrow[0]; lf1 = lrow[1]; lf2 = lrow[2]; lf3 = lrow[3];
        const float4* orow = (const float4*)(outputs + row0 * N_COLS);
        of0 = orow[tid];       of1 = orow[tid + 256];
        of2 = orow[tid + 512]; of3 = orow[tid + 768];
    }
    float xsum_cur = (of0.x + of0.y + of0.z + of0.w)
                   + (of1.x + of1.y + of1.z + of1.w)
                   + (of2.x + of2.y + of2.z + of2.w)
                   + (of3.x + of3.y + of3.z + of3.w);
    {
        ushort4* e4 = (ushort4*)ebuf[0];
        ushort4 s;
        s.x = f2bf(exp2f(of0.x * LOG2E)); s.y = f2bf(exp2f(of0.y * LOG2E));
        s.z = f2bf(exp2f(of0.z * LOG2E)); s.w = f2bf(exp2f(of0.w * LOG2E));
        e4[tid] = s;
        s.x = f2bf(exp2f(of1.x * LOG2E)); s.y = f2bf(exp2f(of1.y * LOG2E));
        s.z = f2bf(exp2f(of1.z * LOG2E)); s.w = f2bf(exp2f(of1.w * LOG2E));
        e4[tid + 256] = s;
        s.x = f2bf(exp2f(of2.x * LOG2E)); s.y = f2bf(exp2f(of2.y * LOG2E));
        s.z = f2bf(exp2f(of2.z * LOG2E)); s.w = f2bf(exp2f(of2.w * LOG2E));
        e4[tid + 512] = s;
        s.x = f2bf(exp2f(of3.x * LOG2E)); s.y = f2bf(exp2f(of3.y * LOG2E));
        s.z = f2bf(exp2f(of3.z * LOG2E)); s.w = f2bf(exp2f(of3.w * LOG2E));
        e4[tid + 768] = s;
    }
    __syncthreads();

    float total_contrib = 0.0f;
    int cur = 0;

    for (int k = 0; k < ROWS; ++k) {
        // current row labels -> static-indexed array
        int labs[PER_THREAD] = { lf0.x, lf0.y, lf0.z, lf0.w,
                                 lf1.x, lf1.y, lf1.z, lf1.w,
                                 lf2.x, lf2.y, lf2.z, lf2.w,
                                 lf3.x, lf3.y, lf3.z, lf3.w };

        // issue next-row loads (labels first, outputs second)
        if (k + 1 < ROWS) {
            const int4* lrow = (const int4*)(labels + (row0 + k + 1) * N_COLS + start);
            lf0 = lrow[0]; lf1 = lrow[1]; lf2 = lrow[2]; lf3 = lrow[3];
            const float4* orow = (const float4*)(outputs + (row0 + k + 1) * N_COLS);
            of0 = orow[tid];       of1 = orow[tid + 256];
            of2 = orow[tid + 512]; of3 = orow[tid + 768];
        }

        // gather bf16 e-values in label order; thread-local prefix sums
        const unsigned short* cb = ebuf[cur];
        float p[PER_THREAD];
        float run = 0.0f;
        #pragma unroll
        for (int j = 0; j < PER_THREAD; ++j) {
            run += bf2f(cb[labs[j]]);
            p[j] = run;
        }

        // wave-level inclusive scan of thread totals
        float inc = run;
        #pragma unroll
        for (int d = 1; d < 64; d <<= 1) {
            float v = __shfl_up(inc, d, 64);
            if (lane >= d) inc += v;
        }
        float excl = inc - run;
        if (lane == 63) wave_t[wid] = inc;

        // lgkm-only barrier: prefetch loads stay in flight
        asm volatile("s_waitcnt lgkmcnt(0)" ::: "memory");
        __builtin_amdgcn_s_barrier();

        float E = excl;
        #pragma unroll
        for (int w = 0; w < NWAVES - 1; ++w)
            if (w < wid) E += wave_t[w];

        // stage next row (vmcnt wait lands here); overlapped with log2s below
        float xsum_next = 0.0f;
        if (k + 1 < ROWS) {
            xsum_next = (of0.x + of0.y + of0.z + of0.w)
                      + (of1.x + of1.y + of1.z + of1.w)
                      + (of2.x + of2.y + of2.z + of2.w)
                      + (of3.x + of3.y + of3.z + of3.w);
            ushort4* e4 = (ushort4*)ebuf[cur ^ 1];
            ushort4 s;
            s.x = f2bf(exp2f(of0.x * LOG2E)); s.y = f2bf(exp2f(of0.y * LOG2E));
            s.z = f2bf(exp2f(of0.z * LOG2E)); s.w = f2bf(exp2f(of0.w * LOG2E));
            e4[tid] = s;
            s.x = f2bf(exp2f(of1.x * LOG2E)); s.y = f2bf(exp2f(of1.y * LOG2E));
            s.z = f2bf(exp2f(of1.z * LOG2E)); s.w = f2bf(exp2f(of1.w * LOG2E));
            e4[tid + 256] = s;
            s.x = f2bf(exp2f(of2.x * LOG2E)); s.y = f2bf(exp2f(of2.y * LOG2E));
            s.z = f2bf(exp2f(of2.z * LOG2E)); s.w = f2bf(exp2f(of2.w * LOG2E));
            e4[tid + 512] = s;
            s.x = f2bf(exp2f(of3.x * LOG2E)); s.y = f2bf(exp2f(of3.y * LOG2E));
            s.z = f2bf(exp2f(of3.z * LOG2E)); s.w = f2bf(exp2f(of3.w * LOG2E));
            e4[tid + 768] = s;
        }

        // scores: 16 independent log2s (overlap the staging writes)
        float acc = 0.0f;
        #pragma unroll
        for (int j = 0; j < PER_THREAD; ++j)
            acc += __log2f(E + p[j]);
        total_contrib += LN2 * acc - xsum_cur;
        xsum_cur = xsum_next;

        __syncthreads();   // row boundary: buffer cur^1 fully staged
        cur ^= 1;
    }

    // ---- block reduce total contribution, plain store per block ----
    #pragma unroll
    for (int d = 32; d > 0; d >>= 1)
        total_contrib += __shfl_down(total_contrib, d, 64);
    if (lane == 0) wsum[wid] = total_contrib;
    __syncthreads();
    if (tid == 0) {
        float tot = 0.0f;
        #pragma unroll
        for (int w = 0; w < NWAVES; ++w) tot += wsum[w];
        partials[blockIdx.x] = (double)tot;
    }
}

// One block: reduce partial doubles, write mean as float.
__global__ __launch_bounds__(BLOCK) void listmle_reduce_kernel(
    const double* __restrict__ partials,
    float* __restrict__ out,
    int nblocks,
    double inv_count)
{
    __shared__ double wtot[NWAVES];
    const int tid  = threadIdx.x;
    const int lane = tid & 63;
    const int wid  = tid >> 6;

    double sum = 0.0;
    for (int i = tid; i < nblocks; i += BLOCK)
        sum += partials[i];

    #pragma unroll
    for (int d = 32; d > 0; d >>= 1)
        sum += __shfl_down(sum, d, 64);
    if (lane == 0) wtot[wid] = sum;
    __syncthreads();
    if (tid == 0) {
        double tot = 0.0;
        #pragma unroll
        for (int w = 0; w < NWAVES; ++w) tot += wtot[w];
        out[0] = (float)(tot * inv_count);
    }
}

extern "C" void kernel_launch(void* const* d_in, const int* in_sizes, int n_in,
                              void* d_out, int out_size, void* d_ws, size_t ws_size,
                              hipStream_t stream)
{
    const float* outputs = (const float*)d_in[0];
    const int*   labels  = (const int*)d_in[1];
    float*  out = (float*)d_out;
    double* partials = (double*)d_ws;

    const int total = in_sizes[0];          // B * N
    const int B = total / N_COLS;           // 8192
    const int nblocks = B / ROWS;           // 2048

    listmle_rows_kernel<<<nblocks, BLOCK, 0, stream>>>(outputs, labels, partials);
    listmle_reduce_kernel<<<1, BLOCK, 0, stream>>>(partials, out, nblocks,
                                                   1.0 / (double)total);
}

// Round 10
// 70.434 us; speedup vs baseline: 2.2400x; 2.0223x over previous
//
#include <hip/hip_runtime.h>
#include <hip/hip_bf16.h>

// ListMLE: mean(cumlogsumexp(gather(outputs, labels), axis=1) - outputs)
// B=8192 rows, N=4096 cols. outputs fp32, labels int32 (per-row permutation).
// R10: R8/R9 composition (reg-prefetch pipeline + bf16 e-value double buffer),
//      but with launch_bounds(256,4) -- the only bound that has never spilled
//      (R6: 52 VGPR @ budget 128). (256,8) and (256,6) both forced spills
//      (WRITE_SIZE 303/245 MB). Actual occupancy follows the ACTUAL allocation:
//      if this lands <=64 VGPR we get 8 blocks/CU (LDS 16.9 KB allows 9);
//      at 65-80 we get 6-7. Either >= R6's 4.

#define N_COLS 4096
#define BLOCK 256
#define PER_THREAD (N_COLS / BLOCK)  // 16
#define NWAVES (BLOCK / 64)          // 4
#define ROWS 4
#define LOG2E 1.4426950408889634f
#define LN2   0.6931471805599453f

__device__ __forceinline__ unsigned short f2bf(float f) {
    union { float f; unsigned u; } v; v.f = f;
    unsigned u = v.u + 0x7FFF + ((v.u >> 16) & 1);   // round-to-nearest-even
    return (unsigned short)(u >> 16);
}
__device__ __forceinline__ float bf2f(unsigned short h) {
    union { unsigned u; float f; } v; v.u = ((unsigned)h) << 16;
    return v.f;
}

__global__ __launch_bounds__(BLOCK, 4) void listmle_rows_kernel(
    const float* __restrict__ outputs,
    const int*   __restrict__ labels,
    double*      __restrict__ partials)
{
    __shared__ unsigned short ebuf[2][N_COLS];   // 2 x 8 KB bf16 e-values
    __shared__ float wave_t[NWAVES];
    __shared__ float wsum[NWAVES];

    const int tid  = threadIdx.x;
    const int lane = tid & 63;
    const int wid  = tid >> 6;
    const size_t row0  = (size_t)blockIdx.x * ROWS;
    const int    start = tid * PER_THREAD;

    // ---- prologue: row 0 -> regs; xsum0; stage buf 0 ----
    int4   lf0, lf1, lf2, lf3;
    float4 of0, of1, of2, of3;
    {
        const int4* lrow = (const int4*)(labels + row0 * N_COLS + start);
        lf0 = lrow[0]; lf1 = lrow[1]; lf2 = lrow[2]; lf3 = lrow[3];
        const float4* orow = (const float4*)(outputs + row0 * N_COLS);
        of0 = orow[tid];       of1 = orow[tid + 256];
        of2 = orow[tid + 512]; of3 = orow[tid + 768];
    }
    float xsum_cur = (of0.x + of0.y + of0.z + of0.w)
                   + (of1.x + of1.y + of1.z + of1.w)
                   + (of2.x + of2.y + of2.z + of2.w)
                   + (of3.x + of3.y + of3.z + of3.w);
    {
        ushort4* e4 = (ushort4*)ebuf[0];
        ushort4 s;
        s.x = f2bf(exp2f(of0.x * LOG2E)); s.y = f2bf(exp2f(of0.y * LOG2E));
        s.z = f2bf(exp2f(of0.z * LOG2E)); s.w = f2bf(exp2f(of0.w * LOG2E));
        e4[tid] = s;
        s.x = f2bf(exp2f(of1.x * LOG2E)); s.y = f2bf(exp2f(of1.y * LOG2E));
        s.z = f2bf(exp2f(of1.z * LOG2E)); s.w = f2bf(exp2f(of1.w * LOG2E));
        e4[tid + 256] = s;
        s.x = f2bf(exp2f(of2.x * LOG2E)); s.y = f2bf(exp2f(of2.y * LOG2E));
        s.z = f2bf(exp2f(of2.z * LOG2E)); s.w = f2bf(exp2f(of2.w * LOG2E));
        e4[tid + 512] = s;
        s.x = f2bf(exp2f(of3.x * LOG2E)); s.y = f2bf(exp2f(of3.y * LOG2E));
        s.z = f2bf(exp2f(of3.z * LOG2E)); s.w = f2bf(exp2f(of3.w * LOG2E));
        e4[tid + 768] = s;
    }
    __syncthreads();

    float total_contrib = 0.0f;
    int cur = 0;

    for (int k = 0; k < ROWS; ++k) {
        // current row labels -> static-indexed array
        int labs[PER_THREAD] = { lf0.x, lf0.y, lf0.z, lf0.w,
                                 lf1.x, lf1.y, lf1.z, lf1.w,
                                 lf2.x, lf2.y, lf2.z, lf2.w,
                                 lf3.x, lf3.y, lf3.z, lf3.w };

        // issue next-row loads (labels first, outputs second)
        if (k + 1 < ROWS) {
            const int4* lrow = (const int4*)(labels + (row0 + k + 1) * N_COLS + start);
            lf0 = lrow[0]; lf1 = lrow[1]; lf2 = lrow[2]; lf3 = lrow[3];
            const float4* orow = (const float4*)(outputs + (row0 + k + 1) * N_COLS);
            of0 = orow[tid];       of1 = orow[tid + 256];
            of2 = orow[tid + 512]; of3 = orow[tid + 768];
        }

        // gather bf16 e-values in label order; thread-local prefix sums
        const unsigned short* cb = ebuf[cur];
        float p[PER_THREAD];
        float run = 0.0f;
        #pragma unroll
        for (int j = 0; j < PER_THREAD; ++j) {
            run += bf2f(cb[labs[j]]);
            p[j] = run;
        }

        // wave-level inclusive scan of thread totals
        float inc = run;
        #pragma unroll
        for (int d = 1; d < 64; d <<= 1) {
            float v = __shfl_up(inc, d, 64);
            if (lane >= d) inc += v;
        }
        float excl = inc - run;
        if (lane == 63) wave_t[wid] = inc;

        // lgkm-only barrier: prefetch loads stay in flight
        asm volatile("s_waitcnt lgkmcnt(0)" ::: "memory");
        __builtin_amdgcn_s_barrier();

        float E = excl;
        #pragma unroll
        for (int w = 0; w < NWAVES - 1; ++w)
            if (w < wid) E += wave_t[w];

        // stage next row (vmcnt wait lands here); overlapped with log2s below
        float xsum_next = 0.0f;
        if (k + 1 < ROWS) {
            xsum_next = (of0.x + of0.y + of0.z + of0.w)
                      + (of1.x + of1.y + of1.z + of1.w)
                      + (of2.x + of2.y + of2.z + of2.w)
                      + (of3.x + of3.y + of3.z + of3.w);
            ushort4* e4 = (ushort4*)ebuf[cur ^ 1];
            ushort4 s;
            s.x = f2bf(exp2f(of0.x * LOG2E)); s.y = f2bf(exp2f(of0.y * LOG2E));
            s.z = f2bf(exp2f(of0.z * LOG2E)); s.w = f2bf(exp2f(of0.w * LOG2E));
            e4[tid] = s;
            s.x = f2bf(exp2f(of1.x * LOG2E)); s.y = f2bf(exp2f(of1.y * LOG2E));
            s.z = f2bf(exp2f(of1.z * LOG2E)); s.w = f2bf(exp2f(of1.w * LOG2E));
            e4[tid + 256] = s;
            s.x = f2bf(exp2f(of2.x * LOG2E)); s.y = f2bf(exp2f(of2.y * LOG2E));
            s.z = f2bf(exp2f(of2.z * LOG2E)); s.w = f2bf(exp2f(of2.w * LOG2E));
            e4[tid + 512] = s;
            s.x = f2bf(exp2f(of3.x * LOG2E)); s.y = f2bf(exp2f(of3.y * LOG2E));
            s.z = f2bf(exp2f(of3.z * LOG2E)); s.w = f2bf(exp2f(of3.w * LOG2E));
            e4[tid + 768] = s;
        }

        // scores: 16 independent log2s (overlap the staging writes)
        float acc = 0.0f;
        #pragma unroll
        for (int j = 0; j < PER_THREAD; ++j)
            acc += __log2f(E + p[j]);
        total_contrib += LN2 * acc - xsum_cur;
        xsum_cur = xsum_next;

        __syncthreads();   // row boundary: buffer cur^1 fully staged
        cur ^= 1;
    }

    // ---- block reduce total contribution, plain store per block ----
    #pragma unroll
    for (int d = 32; d > 0; d >>= 1)
        total_contrib += __shfl_down(total_contrib, d, 64);
    if (lane == 0) wsum[wid] = total_contrib;
    __syncthreads();
    if (tid == 0) {
        float tot = 0.0f;
        #pragma unroll
        for (int w = 0; w < NWAVES; ++w) tot += wsum[w];
        partials[blockIdx.x] = (double)tot;
    }
}

// One block: reduce partial doubles, write mean as float.
__global__ __launch_bounds__(BLOCK) void listmle_reduce_kernel(
    const double* __restrict__ partials,
    float* __restrict__ out,
    int nblocks,
    double inv_count)
{
    __shared__ double wtot[NWAVES];
    const int tid  = threadIdx.x;
    const int lane = tid & 63;
    const int wid  = tid >> 6;

    double sum = 0.0;
    for (int i = tid; i < nblocks; i += BLOCK)
        sum += partials[i];

    #pragma unroll
    for (int d = 32; d > 0; d >>= 1)
        sum += __shfl_down(sum, d, 64);
    if (lane == 0) wtot[wid] = sum;
    __syncthreads();
    if (tid == 0) {
        double tot = 0.0;
        #pragma unroll
        for (int w = 0; w < NWAVES; ++w) tot += wtot[w];
        out[0] = (float)(tot * inv_count);
    }
}

extern "C" void kernel_launch(void* const* d_in, const int* in_sizes, int n_in,
                              void* d_out, int out_size, void* d_ws, size_t ws_size,
                              hipStream_t stream)
{
    const float* outputs = (const float*)d_in[0];
    const int*   labels  = (const int*)d_in[1];
    float*  out = (float*)d_out;
    double* partials = (double*)d_ws;

    const int total = in_sizes[0];          // B * N
    const int B = total / N_COLS;           // 8192
    const int nblocks = B / ROWS;           // 2048

    listmle_rows_kernel<<<nblocks, BLOCK, 0, stream>>>(outputs, labels, partials);
    listmle_reduce_kernel<<<1, BLOCK, 0, stream>>>(partials, out, nblocks,
                                                   1.0 / (double)total);
}